// Round 7
// baseline (105.119 us; speedup 1.0000x reference)
//
#include <hip/hip_runtime.h>

// 16-step spike recurrence, elementwise.
// z_t = (v_t > T_t) since (v-T)/(|v|+1) > 0 <=> v > T (denominator >= 1).
// R7: register double-buffer software pipeline. Each thread: 8 stages of
// 4x f32x4; issue next stage's loads BEFORE computing current stage, so
// each wave's HBM latency hides under its own 48-op VALU chain.
// nt stores (keep L3 for x) + zn in {0,-1} packed-fma formulation kept.

typedef float f32x4 __attribute__((ext_vector_type(4)));

__device__ __constant__ const float kH[16] = {
    -0.73437643f, 3.319645f,   2.1290164f,  3.6901689f,
    3.302721f,    3.2154958f,  2.9151256f,  3.1718695f,
    3.1084518f,   2.6179547f,  2.235003f,   1.2864777f,
    0.52327204f, -0.08344932f, -1.8249638f, 3.0859442f};

__device__ __constant__ const float kD[16] = {
    3.3848417f, -0.07072583f, 3.691287f,   3.3074934f,
    3.2120926f,  2.9196491f,  3.1727686f,  3.1054153f,
    2.621943f,   2.2355895f,  1.2878408f,  0.52468026f,
    0.12632068f, 0.14482783f, 0.3153498f,  0.13054803f};

__device__ __constant__ const float kT[16] = {
    3.1538513f, -1.0211663f,  1.3714716f,  1.0718397f,
    1.0049332f,  0.68078244f, 1.0151638f,  0.8858697f,
    0.4037103f,  0.01490025f, -0.90781677f, -1.6859558f,
    -1.9241625f, -2.0441303f, 0.279356f,   0.1315174f};

__device__ __forceinline__ f32x4 splat4(float s) {
    f32x4 r = {s, s, s, s};
    return r;
}

__device__ __forceinline__ f32x4 spike4(f32x4 v) {
    f32x4 zn = splat4(0.0f);   // zn = -z, in {0, -1}
    f32x4 o  = splat4(0.0f);
#pragma unroll
    for (int t = 0; t < 16; ++t) {
        v = __builtin_elementwise_fma(zn, splat4(kH[t]), v);  // v -= z*H[t]
        zn.x = (v.x > kT[t]) ? -1.0f : 0.0f;
        zn.y = (v.y > kT[t]) ? -1.0f : 0.0f;
        zn.z = (v.z > kT[t]) ? -1.0f : 0.0f;
        zn.w = (v.w > kT[t]) ? -1.0f : 0.0f;
        o = __builtin_elementwise_fma(zn, splat4(-kD[t]), o); // o += z*D[t]
    }
    return o;
}

// Pipelined fast path: each thread handles NIT stages of 4 f32x4 at
// stride T; grid sized so coverage is exact (n4 == 4*NIT*T).
template <int NIT>
__global__ __launch_bounds__(256, 4) void spike_pipe(const f32x4* __restrict__ x,
                                                     f32x4* __restrict__ out) {
    const int T = gridDim.x * blockDim.x;
    const int t = blockIdx.x * blockDim.x + threadIdx.x;
    const int G = 4 * T;

    f32x4 A0 = x[t], A1 = x[t + T], A2 = x[t + 2 * T], A3 = x[t + 3 * T];
    f32x4 B0, B1, B2, B3;

#pragma unroll
    for (int g = 0; g < NIT; g += 2) {
        // Issue next stage's loads (B) before computing A.
        if (g + 1 < NIT) {
            const int b = t + (g + 1) * G;
            B0 = x[b]; B1 = x[b + T]; B2 = x[b + 2 * T]; B3 = x[b + 3 * T];
        }
        {
            const int a = t + g * G;
            __builtin_nontemporal_store(spike4(A0), &out[a]);
            __builtin_nontemporal_store(spike4(A1), &out[a + T]);
            __builtin_nontemporal_store(spike4(A2), &out[a + 2 * T]);
            __builtin_nontemporal_store(spike4(A3), &out[a + 3 * T]);
        }
        // Issue stage g+2's loads (A) before computing B.
        if (g + 2 < NIT) {
            const int a = t + (g + 2) * G;
            A0 = x[a]; A1 = x[a + T]; A2 = x[a + 2 * T]; A3 = x[a + 3 * T];
        }
        if (g + 1 < NIT) {
            const int b = t + (g + 1) * G;
            __builtin_nontemporal_store(spike4(B0), &out[b]);
            __builtin_nontemporal_store(spike4(B1), &out[b + T]);
            __builtin_nontemporal_store(spike4(B2), &out[b + 2 * T]);
            __builtin_nontemporal_store(spike4(B3), &out[b + 3 * T]);
        }
    }
}

// Generic fallback (any n4): R5-style 4-deep grid-stride.
__global__ __launch_bounds__(256) void spike_generic(const f32x4* __restrict__ x,
                                                     f32x4* __restrict__ out,
                                                     int n4) {
    const int T = gridDim.x * blockDim.x;
    int i = blockIdx.x * blockDim.x + threadIdx.x;
    for (; i + 3 * T < n4; i += 4 * T) {
        f32x4 r0 = spike4(x[i]);
        f32x4 r1 = spike4(x[i + T]);
        f32x4 r2 = spike4(x[i + 2 * T]);
        f32x4 r3 = spike4(x[i + 3 * T]);
        __builtin_nontemporal_store(r0, &out[i]);
        __builtin_nontemporal_store(r1, &out[i + T]);
        __builtin_nontemporal_store(r2, &out[i + 2 * T]);
        __builtin_nontemporal_store(r3, &out[i + 3 * T]);
    }
    for (; i < n4; i += T) {
        f32x4 r = spike4(x[i]);
        __builtin_nontemporal_store(r, &out[i]);
    }
}

extern "C" void kernel_launch(void* const* d_in, const int* in_sizes, int n_in,
                              void* d_out, int out_size, void* d_ws, size_t ws_size,
                              hipStream_t stream) {
    const float* x = (const float*)d_in[0];
    float* out = (float*)d_out;
    int n = in_sizes[0];          // 16*4096*1024 = 67,108,864
    int n4 = n >> 2;              // 16,777,216 float4

    const int block = 256;
    constexpr int NIT = 8;                    // 32 f32x4 per thread
    const int per_thread = 4 * NIT;           // f32x4 per thread

    if (n4 % (block * per_thread) == 0) {
        int grid = n4 / (block * per_thread); // 2048 for the bench shape
        spike_pipe<NIT><<<grid, block, 0, stream>>>(
            (const f32x4*)x, (f32x4*)out);
    } else {
        int grid = (n4 + 4 * block - 1) / (4 * block);
        if (grid > 2048) grid = 2048;
        spike_generic<<<grid, block, 0, stream>>>(
            (const f32x4*)x, (f32x4*)out, n4);
    }
}

// Round 8
// 83.639 us; speedup vs baseline: 1.2568x; 1.2568x over previous
//
#include <hip/hip_runtime.h>

// 16-step spike recurrence, elementwise.
// z_t = (v_t > T_t) since (v-T)/(|v|+1) > 0 <=> v > T (denominator >= 1).
// R8: VALU-bound fix. z computed WITHOUT compare/select:
//   z = clamp(fma(v, 2^40, -T*2^40))   -- v_pk_fma_f32 ... clamp
// Sign of fma is exact => z==1.0 iff v>T (min nonzero |v-T| >= 2^-30,
// scaled >= 2^10 >= 1; exact tie gives +0 -> z=0, matching v>T false).
// All updates via packed fp32 fma: 3 pk-instr per 2 elems per step
// (was ~8 scalar). R5's winning structure kept: exact-cover 16384 blocks,
// 4x f32x4 per thread, nontemporal stores.

typedef float f32x2 __attribute__((ext_vector_type(2)));
typedef float f32x4 __attribute__((ext_vector_type(4)));

static constexpr float kBIG = 1099511627776.0f;  // 2^40 (exact scale)

static constexpr float kH[16] = {
    -0.73437643f, 3.319645f,   2.1290164f,  3.6901689f,
    3.302721f,    3.2154958f,  2.9151256f,  3.1718695f,
    3.1084518f,   2.6179547f,  2.235003f,   1.2864777f,
    0.52327204f, -0.08344932f, -1.8249638f, 3.0859442f};

static constexpr float kD[16] = {
    3.3848417f, -0.07072583f, 3.691287f,   3.3074934f,
    3.2120926f,  2.9196491f,  3.1727686f,  3.1054153f,
    2.621943f,   2.2355895f,  1.2878408f,  0.52468026f,
    0.12632068f, 0.14482783f, 0.3153498f,  0.13054803f};

static constexpr float kT[16] = {
    3.1538513f, -1.0211663f,  1.3714716f,  1.0718397f,
    1.0049332f,  0.68078244f, 1.0151638f,  0.8858697f,
    0.4037103f,  0.01490025f, -0.90781677f, -1.6859558f,
    -1.9241625f, -2.0441303f, 0.279356f,   0.1315174f};

__device__ __forceinline__ f32x2 pk_fma(f32x2 a, f32x2 b, f32x2 c) {
    f32x2 d;
    asm("v_pk_fma_f32 %0, %1, %2, %3" : "=v"(d) : "v"(a), "v"(b), "v"(c));
    return d;
}

__device__ __forceinline__ f32x2 pk_fma_clamp(f32x2 a, f32x2 b, f32x2 c) {
    f32x2 d;
    asm("v_pk_fma_f32 %0, %1, %2, %3 clamp" : "=v"(d) : "v"(a), "v"(b), "v"(c));
    return d;
}

// Process 8 f32x2 pairs (16 elems) through all 16 steps; constants
// amortize across the 24 pk-ops per step.
__device__ __forceinline__ void spike8(f32x2 v[8], f32x2 o[8]) {
    const f32x2 big = {kBIG, kBIG};
    f32x2 z[8];
    {   // t = 0: z_{-1}=0 so v unchanged; o = z*D0.
        const f32x2 ts = {-kT[0] * kBIG, -kT[0] * kBIG};
        const f32x2 dd = {kD[0], kD[0]};
        const f32x2 zz = {0.0f, 0.0f};
#pragma unroll
        for (int c = 0; c < 8; ++c) {
            z[c] = pk_fma_clamp(v[c], big, ts);   // z = (v>T0)
            o[c] = pk_fma(z[c], dd, zz);          // o = z*D0 (exact)
        }
    }
#pragma unroll
    for (int t = 1; t < 16; ++t) {
        const f32x2 nh = {-kH[t], -kH[t]};
        const f32x2 ts = {-kT[t] * kBIG, -kT[t] * kBIG};
        const f32x2 dd = {kD[t], kD[t]};
#pragma unroll
        for (int c = 0; c < 8; ++c) {
            v[c] = pk_fma(z[c], nh, v[c]);        // v -= z_{t-1}*H[t] (exact)
            z[c] = pk_fma_clamp(v[c], big, ts);   // z = (v>T[t])
            o[c] = pk_fma(z[c], dd, o[c]);        // o += z*D[t] (1 rounding,
        }                                         //  == ref since z*D exact)
    }
}

// Exact-cover fast path: each thread owns 4 f32x4 at stride T.
__global__ __launch_bounds__(256) void spike_kernel(const f32x4* __restrict__ x,
                                                    f32x4* __restrict__ out) {
    const int T = gridDim.x * blockDim.x;
    const int i = blockIdx.x * blockDim.x + threadIdx.x;

    f32x4 a0 = x[i];
    f32x4 a1 = x[i + T];
    f32x4 a2 = x[i + 2 * T];
    f32x4 a3 = x[i + 3 * T];

    f32x2 v[8] = {a0.xy, a0.zw, a1.xy, a1.zw, a2.xy, a2.zw, a3.xy, a3.zw};
    f32x2 o[8];
    spike8(v, o);

    f32x4 r0 = {o[0].x, o[0].y, o[1].x, o[1].y};
    f32x4 r1 = {o[2].x, o[2].y, o[3].x, o[3].y};
    f32x4 r2 = {o[4].x, o[4].y, o[5].x, o[5].y};
    f32x4 r3 = {o[6].x, o[6].y, o[7].x, o[7].y};

    __builtin_nontemporal_store(r0, &out[i]);
    __builtin_nontemporal_store(r1, &out[i + T]);
    __builtin_nontemporal_store(r2, &out[i + 2 * T]);
    __builtin_nontemporal_store(r3, &out[i + 3 * T]);
}

// Generic fallback (any n4), plain math — reference-exact.
__device__ __forceinline__ float spike_chain(float v) {
    float z = (v > kT[0]) ? 1.0f : 0.0f;
    float out = z * kD[0];
#pragma unroll
    for (int t = 1; t < 16; ++t) {
        v = fmaf(-z, kH[t], v);
        z = (v > kT[t]) ? 1.0f : 0.0f;
        out = fmaf(z, kD[t], out);
    }
    return out;
}

__global__ __launch_bounds__(256) void spike_generic(const f32x4* __restrict__ x,
                                                     f32x4* __restrict__ out,
                                                     int n4) {
    const int T = gridDim.x * blockDim.x;
    int i = blockIdx.x * blockDim.x + threadIdx.x;
    for (; i < n4; i += T) {
        f32x4 a = x[i];
        f32x4 r;
        r.x = spike_chain(a.x);
        r.y = spike_chain(a.y);
        r.z = spike_chain(a.z);
        r.w = spike_chain(a.w);
        __builtin_nontemporal_store(r, &out[i]);
    }
}

extern "C" void kernel_launch(void* const* d_in, const int* in_sizes, int n_in,
                              void* d_out, int out_size, void* d_ws, size_t ws_size,
                              hipStream_t stream) {
    const float* x = (const float*)d_in[0];
    float* out = (float*)d_out;
    int n = in_sizes[0];          // 16*4096*1024 = 67,108,864
    int n4 = n >> 2;              // 16,777,216 float4

    const int block = 256;
    const int per_thread = 4;     // f32x4 per thread

    if (n4 % (block * per_thread) == 0) {
        int grid = n4 / (block * per_thread);   // 16384 for the bench shape
        spike_kernel<<<grid, block, 0, stream>>>(
            (const f32x4*)x, (f32x4*)out);
    } else {
        int grid = (n4 + block - 1) / block;
        if (grid > 4096) grid = 4096;
        spike_generic<<<grid, block, 0, stream>>>(
            (const f32x4*)x, (f32x4*)out, n4);
    }
}